// Round 2
// baseline (1217.732 us; speedup 1.0000x reference)
//
#include <hip/hip_runtime.h>

#define N_USERS 200000
#define N_ITEMS 100000
#define N_NODES (N_USERS + N_ITEMS)
#define N_EDGES 1250000
#define DIM 64
#define EPS 1e-12f

// Scatter-add phase: 16 threads per edge, each handles 4 consecutive dims via float4.
__global__ void lightgcn_scatter(const float* __restrict__ user_emb,
                                 const float* __restrict__ item_emb,
                                 const int* __restrict__ src,
                                 const int* __restrict__ dst,
                                 const float* __restrict__ ew,
                                 float* __restrict__ agg) {
    int idx = blockIdx.x * blockDim.x + threadIdx.x;
    int e = idx >> 4;
    if (e >= N_EDGES) return;
    int q = idx & 15;

    int s = src[e];
    int d = dst[e];
    float w = ew[e];

    const float* hrow = (s < N_USERS)
        ? (user_emb + (size_t)s * DIM)
        : (item_emb + (size_t)(s - N_USERS) * DIM);

    float4 v = *reinterpret_cast<const float4*>(hrow + q * 4);

    float* orow = agg + (size_t)d * DIM + q * 4;
    atomicAdd(orow + 0, v.x * w);
    atomicAdd(orow + 1, v.y * w);
    atomicAdd(orow + 2, v.z * w);
    atomicAdd(orow + 3, v.w * w);
}

// Row L2-normalize in place: one 64-lane wave per node, lane = dim.
__global__ void lightgcn_normalize(float* __restrict__ agg) {
    int gtid = blockIdx.x * blockDim.x + threadIdx.x;
    int node = gtid >> 6;
    int lane = threadIdx.x & 63;
    if (node >= N_NODES) return;

    float v = agg[(size_t)node * DIM + lane];
    float ss = v * v;
    #pragma unroll
    for (int off = 32; off > 0; off >>= 1)
        ss += __shfl_xor(ss, off, 64);

    float denom = fmaxf(sqrtf(ss), EPS);
    agg[(size_t)node * DIM + lane] = v / denom;
}

extern "C" void kernel_launch(void* const* d_in, const int* in_sizes, int n_in,
                              void* d_out, int out_size, void* d_ws, size_t ws_size,
                              hipStream_t stream) {
    const float* user_emb = (const float*)d_in[0];
    const float* item_emb = (const float*)d_in[1];
    const int* src        = (const int*)d_in[2];
    const int* dst        = (const int*)d_in[3];
    const float* ew       = (const float*)d_in[4];
    float* out            = (float*)d_out;

    // d_out is poisoned to 0xAA before every launch — zero it (async, capture-safe).
    hipMemsetAsync(out, 0, (size_t)N_NODES * DIM * sizeof(float), stream);

    // Scatter-add: E * 16 threads.
    {
        long long total = (long long)N_EDGES * 16;
        int block = 256;
        int grid = (int)((total + block - 1) / block);
        lightgcn_scatter<<<grid, block, 0, stream>>>(user_emb, item_emb, src, dst, ew, out);
    }

    // Normalize: one wave per node.
    {
        long long total = (long long)N_NODES * 64;
        int block = 256;
        int grid = (int)((total + block - 1) / block);
        lightgcn_normalize<<<grid, block, 0, stream>>>(out);
    }
}

// Round 5
// 427.106 us; speedup vs baseline: 2.8511x; 2.8511x over previous
//
#include <hip/hip_runtime.h>

#define N_USERS 200000
#define N_ITEMS 100000
#define N_NODES (N_USERS + N_ITEMS)
#define N_EDGES 1250000
#define DIM 64
#define EPS 1e-12f

#define SCAN_THREADS 256
#define ELEMS_PER_THREAD 4
#define ELEMS_PER_BLOCK (SCAN_THREADS * ELEMS_PER_THREAD)   // 1024
#define NBLK ((N_NODES + ELEMS_PER_BLOCK - 1) / ELEMS_PER_BLOCK)  // 293

// ---- Phase 1: histogram of dst ------------------------------------------
__global__ void hist_kernel(const int* __restrict__ dst, int* __restrict__ deg) {
    int e = blockIdx.x * blockDim.x + threadIdx.x;
    if (e < N_EDGES) atomicAdd(&deg[dst[e]], 1);
}

// ---- Phase 2a: per-block exclusive scan of deg --------------------------
__global__ void scan_block_kernel(const int* __restrict__ deg,
                                  int* __restrict__ off,
                                  int* __restrict__ partials) {
    __shared__ int lds[SCAN_THREADS];
    int t = threadIdx.x;
    int base = blockIdx.x * ELEMS_PER_BLOCK + t * ELEMS_PER_THREAD;

    int v[ELEMS_PER_THREAD];
    #pragma unroll
    for (int k = 0; k < ELEMS_PER_THREAD; k++) {
        int i = base + k;
        v[k] = (i < N_NODES) ? deg[i] : 0;
    }
    int tsum = v[0] + v[1] + v[2] + v[3];

    int val = tsum;
    lds[t] = val;
    __syncthreads();
    for (int o = 1; o < SCAN_THREADS; o <<= 1) {
        int other = (t >= o) ? lds[t - o] : 0;
        __syncthreads();
        val += other;
        lds[t] = val;
        __syncthreads();
    }
    // val is inclusive scan of thread sums; exclusive thread base:
    int run = val - tsum;
    #pragma unroll
    for (int k = 0; k < ELEMS_PER_THREAD; k++) {
        int i = base + k;
        if (i < N_NODES) off[i] = run;
        run += v[k];
    }
    if (t == SCAN_THREADS - 1) partials[blockIdx.x] = val;  // block total
}

// ---- Phase 2b: exclusive scan of the 293 block totals (one block) -------
__global__ void scan_partials_kernel(int* __restrict__ partials) {
    __shared__ int lds[512];
    int t = threadIdx.x;
    int val = (t < NBLK) ? partials[t] : 0;
    int acc = val;
    lds[t] = acc;
    __syncthreads();
    for (int o = 1; o < 512; o <<= 1) {
        int other = (t >= o) ? lds[t - o] : 0;
        __syncthreads();
        acc += other;
        lds[t] = acc;
        __syncthreads();
    }
    if (t < NBLK) partials[t] = acc - val;  // exclusive
}

// ---- Phase 2c: add block bases; init cursors ----------------------------
__global__ void fixup_kernel(int* __restrict__ off,
                             const int* __restrict__ partials,
                             int* __restrict__ cursor) {
    int i = blockIdx.x * blockDim.x + threadIdx.x;
    if (i < N_NODES) {
        int v = off[i] + partials[i / ELEMS_PER_BLOCK];
        off[i] = v;
        cursor[i] = v;
    }
}

// ---- Phase 3: bucket-scatter edges into dst-sorted order ----------------
__global__ void scatter_edges_kernel(const int* __restrict__ src,
                                     const int* __restrict__ dst,
                                     const float* __restrict__ ew,
                                     int* __restrict__ cursor,
                                     int* __restrict__ ssrc,
                                     float* __restrict__ sw) {
    int e = blockIdx.x * blockDim.x + threadIdx.x;
    if (e >= N_EDGES) return;
    int d = dst[e];
    int pos = atomicAdd(&cursor[d], 1);
    ssrc[pos] = src[e];
    sw[pos]   = ew[e];
}

// ---- Phase 4: gather-aggregate + fused L2 normalize ---------------------
// One 64-lane wave per node; lane = dim. Edge (src,w) loaded lane-parallel,
// broadcast via shfl; gather of h[src] row is a coalesced 256B load.
__global__ void aggregate_kernel(const float* __restrict__ user_emb,
                                 const float* __restrict__ item_emb,
                                 const int* __restrict__ off,
                                 const int* __restrict__ deg,
                                 const int* __restrict__ ssrc,
                                 const float* __restrict__ sw,
                                 float* __restrict__ out) {
    int gtid = blockIdx.x * blockDim.x + threadIdx.x;
    int node = gtid >> 6;
    int lane = threadIdx.x & 63;
    if (node >= N_NODES) return;

    int start = off[node];
    int n     = deg[node];

    float acc = 0.f;
    for (int c = 0; c < n; c += 64) {
        int m = n - c;
        if (m > 64) m = 64;
        int   s = 0;
        float w = 0.f;
        if (lane < m) {
            s = ssrc[start + c + lane];
            w = sw[start + c + lane];
        }
        for (int j = 0; j < m; j++) {
            int   sj = __shfl(s, j, 64);
            float wj = __shfl(w, j, 64);
            const float* row = (sj < N_USERS)
                ? (user_emb + (size_t)sj * DIM)
                : (item_emb + (size_t)(sj - N_USERS) * DIM);
            acc = fmaf(wj, row[lane], acc);
        }
    }

    float ss = acc * acc;
    #pragma unroll
    for (int o = 32; o > 0; o >>= 1)
        ss += __shfl_xor(ss, o, 64);

    float denom = fmaxf(sqrtf(ss), EPS);
    out[(size_t)node * DIM + lane] = acc / denom;
}

extern "C" void kernel_launch(void* const* d_in, const int* in_sizes, int n_in,
                              void* d_out, int out_size, void* d_ws, size_t ws_size,
                              hipStream_t stream) {
    const float* user_emb = (const float*)d_in[0];
    const float* item_emb = (const float*)d_in[1];
    const int* src        = (const int*)d_in[2];
    const int* dst        = (const int*)d_in[3];
    const float* ew       = (const float*)d_in[4];
    float* out            = (float*)d_out;

    // Workspace layout (ints): off[N_NODES] | deg[N_NODES] | cursor[N_NODES]
    //                        | partials[512] | ssrc[N_EDGES] | sw[N_EDGES]
    // Total = 13.6 MB. ws is re-poisoned to 0xAA each call; we only need deg zeroed.
    int* off      = (int*)d_ws;
    int* deg      = off + N_NODES;
    int* cursor   = deg + N_NODES;
    int* partials = cursor + N_NODES;
    int* ssrc     = partials + 512;
    float* sw     = (float*)(ssrc + N_EDGES);

    hipMemsetAsync(deg, 0, (size_t)N_NODES * sizeof(int), stream);

    {   // histogram
        int block = 256, grid = (N_EDGES + block - 1) / block;
        hist_kernel<<<grid, block, 0, stream>>>(dst, deg);
    }
    {   // scan
        scan_block_kernel<<<NBLK, SCAN_THREADS, 0, stream>>>(deg, off, partials);
        scan_partials_kernel<<<1, 512, 0, stream>>>(partials);
        int block = 256, grid = (N_NODES + block - 1) / block;
        fixup_kernel<<<grid, block, 0, stream>>>(off, partials, cursor);
    }
    {   // bucket scatter
        int block = 256, grid = (N_EDGES + block - 1) / block;
        scatter_edges_kernel<<<grid, block, 0, stream>>>(src, dst, ew, cursor, ssrc, sw);
    }
    {   // gather-aggregate + normalize (writes every output element)
        long long total = (long long)N_NODES * 64;
        int block = 256;
        int grid = (int)((total + block - 1) / block);
        aggregate_kernel<<<grid, block, 0, stream>>>(user_emb, item_emb, off, deg, ssrc, sw, out);
    }
}

// Round 7
// 343.640 us; speedup vs baseline: 3.5436x; 1.2429x over previous
//
#include <hip/hip_runtime.h>

#define N_USERS 200000
#define N_ITEMS 100000
#define N_NODES (N_USERS + N_ITEMS)
#define N_EDGES 1250000
#define DIM 64
#define EPS 1e-12f

#define SCAN_THREADS 256
#define ELEMS_PER_THREAD 4
#define ELEMS_PER_BLOCK (SCAN_THREADS * ELEMS_PER_THREAD)   // 1024
#define NBLK ((N_NODES + ELEMS_PER_BLOCK - 1) / ELEMS_PER_BLOCK)  // 293

typedef unsigned long long u64;

// ---- Phase 1: histogram of dst (4 edges/thread via int4) ----------------
__global__ void hist_kernel(const int4* __restrict__ dst4, int* __restrict__ deg) {
    int i = blockIdx.x * blockDim.x + threadIdx.x;
    if (i < N_EDGES / 4) {
        int4 d = dst4[i];
        atomicAdd(&deg[d.x], 1);
        atomicAdd(&deg[d.y], 1);
        atomicAdd(&deg[d.z], 1);
        atomicAdd(&deg[d.w], 1);
    }
}

// ---- Phase 2a: per-block exclusive scan of deg --------------------------
__global__ void scan_block_kernel(const int* __restrict__ deg,
                                  int* __restrict__ off,
                                  int* __restrict__ partials) {
    __shared__ int lds[SCAN_THREADS];
    int t = threadIdx.x;
    int base = blockIdx.x * ELEMS_PER_BLOCK + t * ELEMS_PER_THREAD;

    int v[ELEMS_PER_THREAD];
    #pragma unroll
    for (int k = 0; k < ELEMS_PER_THREAD; k++) {
        int i = base + k;
        v[k] = (i < N_NODES) ? deg[i] : 0;
    }
    int tsum = v[0] + v[1] + v[2] + v[3];

    int val = tsum;
    lds[t] = val;
    __syncthreads();
    for (int o = 1; o < SCAN_THREADS; o <<= 1) {
        int other = (t >= o) ? lds[t - o] : 0;
        __syncthreads();
        val += other;
        lds[t] = val;
        __syncthreads();
    }
    int run = val - tsum;
    #pragma unroll
    for (int k = 0; k < ELEMS_PER_THREAD; k++) {
        int i = base + k;
        if (i < N_NODES) off[i] = run;
        run += v[k];
    }
    if (t == SCAN_THREADS - 1) partials[blockIdx.x] = val;
}

// ---- Phase 2b: exclusive scan of the 293 block totals (one block) -------
__global__ void scan_partials_kernel(int* __restrict__ partials) {
    __shared__ int lds[512];
    int t = threadIdx.x;
    int val = (t < NBLK) ? partials[t] : 0;
    int acc = val;
    lds[t] = acc;
    __syncthreads();
    for (int o = 1; o < 512; o <<= 1) {
        int other = (t >= o) ? lds[t - o] : 0;
        __syncthreads();
        acc += other;
        lds[t] = acc;
        __syncthreads();
    }
    if (t < NBLK) partials[t] = acc - val;
}

// ---- Phase 2c: add block bases; init cursors ----------------------------
__global__ void fixup_kernel(int* __restrict__ off,
                             const int* __restrict__ partials,
                             int* __restrict__ cursor) {
    int i = blockIdx.x * blockDim.x + threadIdx.x;
    if (i < N_NODES) {
        int v = off[i] + partials[i / ELEMS_PER_BLOCK];
        off[i] = v;
        cursor[i] = v;
    }
}

// ---- Phase 3: bucket-scatter packed (src, w) into dst-sorted order ------
// 4 edges/thread, vectorized reads, ONE 8B random write per edge.
__global__ void scatter_edges_kernel(const int4* __restrict__ src4,
                                     const int4* __restrict__ dst4,
                                     const float4* __restrict__ ew4,
                                     int* __restrict__ cursor,
                                     u64* __restrict__ edges) {
    int i = blockIdx.x * blockDim.x + threadIdx.x;
    if (i >= N_EDGES / 4) return;
    int4 s = src4[i];
    int4 d = dst4[i];
    float4 w = ew4[i];

    int p0 = atomicAdd(&cursor[d.x], 1);
    int p1 = atomicAdd(&cursor[d.y], 1);
    int p2 = atomicAdd(&cursor[d.z], 1);
    int p3 = atomicAdd(&cursor[d.w], 1);

    edges[p0] = (u64)(unsigned)s.x | ((u64)__float_as_uint(w.x) << 32);
    edges[p1] = (u64)(unsigned)s.y | ((u64)__float_as_uint(w.y) << 32);
    edges[p2] = (u64)(unsigned)s.z | ((u64)__float_as_uint(w.z) << 32);
    edges[p3] = (u64)(unsigned)s.w | ((u64)__float_as_uint(w.w) << 32);
}

// ---- Phase 4: gather-aggregate + fused L2 normalize ---------------------
// 16 lanes per node (lane = dim quad, float4 each), 4 nodes per wave.
// Each group scalar-loads its packed edge (same addr -> broadcast), no shfl.
__global__ void aggregate_kernel(const float* __restrict__ user_emb,
                                 const float* __restrict__ item_emb,
                                 const int* __restrict__ off,
                                 const int* __restrict__ deg,
                                 const u64* __restrict__ edges,
                                 float* __restrict__ out) {
    int gtid = blockIdx.x * blockDim.x + threadIdx.x;
    int node = gtid >> 4;          // 16 threads per node
    int q    = threadIdx.x & 15;   // dim quad: dims [4q, 4q+3]
    if (node >= N_NODES) return;

    int start = off[node];
    int n     = deg[node];

    float4 acc = make_float4(0.f, 0.f, 0.f, 0.f);

    int j = 0;
    // 2-edge unroll: two independent gathers in flight.
    for (; j + 2 <= n; j += 2) {
        u64 pk0 = edges[start + j];
        u64 pk1 = edges[start + j + 1];
        int s0 = (int)(unsigned)(pk0 & 0xffffffffULL);
        int s1 = (int)(unsigned)(pk1 & 0xffffffffULL);
        float w0 = __uint_as_float((unsigned)(pk0 >> 32));
        float w1 = __uint_as_float((unsigned)(pk1 >> 32));
        const float* r0 = (s0 < N_USERS) ? user_emb + (size_t)s0 * DIM
                                         : item_emb + (size_t)(s0 - N_USERS) * DIM;
        const float* r1 = (s1 < N_USERS) ? user_emb + (size_t)s1 * DIM
                                         : item_emb + (size_t)(s1 - N_USERS) * DIM;
        float4 v0 = *reinterpret_cast<const float4*>(r0 + q * 4);
        float4 v1 = *reinterpret_cast<const float4*>(r1 + q * 4);
        acc.x = fmaf(w0, v0.x, acc.x);
        acc.y = fmaf(w0, v0.y, acc.y);
        acc.z = fmaf(w0, v0.z, acc.z);
        acc.w = fmaf(w0, v0.w, acc.w);
        acc.x = fmaf(w1, v1.x, acc.x);
        acc.y = fmaf(w1, v1.y, acc.y);
        acc.z = fmaf(w1, v1.z, acc.z);
        acc.w = fmaf(w1, v1.w, acc.w);
    }
    if (j < n) {
        u64 pk = edges[start + j];
        int s = (int)(unsigned)(pk & 0xffffffffULL);
        float w = __uint_as_float((unsigned)(pk >> 32));
        const float* r = (s < N_USERS) ? user_emb + (size_t)s * DIM
                                       : item_emb + (size_t)(s - N_USERS) * DIM;
        float4 v = *reinterpret_cast<const float4*>(r + q * 4);
        acc.x = fmaf(w, v.x, acc.x);
        acc.y = fmaf(w, v.y, acc.y);
        acc.z = fmaf(w, v.z, acc.z);
        acc.w = fmaf(w, v.w, acc.w);
    }

    // Sum of squares across the node's 16 lanes (xor offsets 1..8 stay in-group).
    float ss = acc.x * acc.x + acc.y * acc.y + acc.z * acc.z + acc.w * acc.w;
    #pragma unroll
    for (int o = 8; o >= 1; o >>= 1)
        ss += __shfl_xor(ss, o, 64);

    float denom = fmaxf(sqrtf(ss), EPS);
    float inv = 1.0f / denom;
    float4 r;
    r.x = acc.x * inv; r.y = acc.y * inv; r.z = acc.z * inv; r.w = acc.w * inv;
    *reinterpret_cast<float4*>(out + (size_t)node * DIM + q * 4) = r;
}

extern "C" void kernel_launch(void* const* d_in, const int* in_sizes, int n_in,
                              void* d_out, int out_size, void* d_ws, size_t ws_size,
                              hipStream_t stream) {
    const float* user_emb = (const float*)d_in[0];
    const float* item_emb = (const float*)d_in[1];
    const int* src        = (const int*)d_in[2];
    const int* dst        = (const int*)d_in[3];
    const float* ew       = (const float*)d_in[4];
    float* out            = (float*)d_out;

    // Workspace (ints): off[N] | deg[N] | cursor[N] | partials[512] | edges[E] (8B)
    // 900512 ints = 3,602,048 B (8B aligned), then 10 MB of packed edges.
    int* off      = (int*)d_ws;
    int* deg      = off + N_NODES;
    int* cursor   = deg + N_NODES;
    int* partials = cursor + N_NODES;
    u64* edges    = (u64*)(partials + 512);

    hipMemsetAsync(deg, 0, (size_t)N_NODES * sizeof(int), stream);

    {   // histogram (4 edges/thread)
        int block = 256, grid = (N_EDGES / 4 + block - 1) / block;
        hist_kernel<<<grid, block, 0, stream>>>((const int4*)dst, deg);
    }
    {   // scan
        scan_block_kernel<<<NBLK, SCAN_THREADS, 0, stream>>>(deg, off, partials);
        scan_partials_kernel<<<1, 512, 0, stream>>>(partials);
        int block = 256, grid = (N_NODES + block - 1) / block;
        fixup_kernel<<<grid, block, 0, stream>>>(off, partials, cursor);
    }
    {   // bucket scatter (4 edges/thread, packed 8B writes)
        int block = 256, grid = (N_EDGES / 4 + block - 1) / block;
        scatter_edges_kernel<<<grid, block, 0, stream>>>(
            (const int4*)src, (const int4*)dst, (const float4*)ew, cursor, edges);
    }
    {   // gather-aggregate + normalize (16 threads/node)
        long long total = (long long)N_NODES * 16;
        int block = 256;
        int grid = (int)((total + block - 1) / block);
        aggregate_kernel<<<grid, block, 0, stream>>>(user_emb, item_emb, off, deg, edges, out);
    }
}

// Round 12
// 334.296 us; speedup vs baseline: 3.6427x; 1.0280x over previous
//
#include <hip/hip_runtime.h>

#define N_USERS 200000
#define N_ITEMS 100000
#define N_NODES (N_USERS + N_ITEMS)
#define N_EDGES 1250000
#define DIM 64
#define EPS 1e-12f

#define SCAN_THREADS 256
#define ELEMS_PER_THREAD 4
#define ELEMS_PER_BLOCK (SCAN_THREADS * ELEMS_PER_THREAD)   // 1024
#define NBLK ((N_NODES + ELEMS_PER_BLOCK - 1) / ELEMS_PER_BLOCK)  // 293

typedef unsigned long long u64;

// ---- Phase 1: histogram of dst (1 edge/thread: max waves to hide atomic latency)
__global__ void hist_kernel(const int* __restrict__ dst, int* __restrict__ deg) {
    int e = blockIdx.x * blockDim.x + threadIdx.x;
    if (e < N_EDGES) atomicAdd(&deg[dst[e]], 1);
}

// ---- Phase 2a: per-block exclusive scan of deg --------------------------
__global__ void scan_block_kernel(const int* __restrict__ deg,
                                  int* __restrict__ off,
                                  int* __restrict__ partials) {
    __shared__ int lds[SCAN_THREADS];
    int t = threadIdx.x;
    int base = blockIdx.x * ELEMS_PER_BLOCK + t * ELEMS_PER_THREAD;

    int v[ELEMS_PER_THREAD];
    #pragma unroll
    for (int k = 0; k < ELEMS_PER_THREAD; k++) {
        int i = base + k;
        v[k] = (i < N_NODES) ? deg[i] : 0;
    }
    int tsum = v[0] + v[1] + v[2] + v[3];

    int val = tsum;
    lds[t] = val;
    __syncthreads();
    for (int o = 1; o < SCAN_THREADS; o <<= 1) {
        int other = (t >= o) ? lds[t - o] : 0;
        __syncthreads();
        val += other;
        lds[t] = val;
        __syncthreads();
    }
    int run = val - tsum;
    #pragma unroll
    for (int k = 0; k < ELEMS_PER_THREAD; k++) {
        int i = base + k;
        if (i < N_NODES) off[i] = run;
        run += v[k];
    }
    if (t == SCAN_THREADS - 1) partials[blockIdx.x] = val;
}

// ---- Phase 2b: exclusive scan of the 293 block totals (one block) -------
__global__ void scan_partials_kernel(int* __restrict__ partials) {
    __shared__ int lds[512];
    int t = threadIdx.x;
    int val = (t < NBLK) ? partials[t] : 0;
    int acc = val;
    lds[t] = acc;
    __syncthreads();
    for (int o = 1; o < 512; o <<= 1) {
        int other = (t >= o) ? lds[t - o] : 0;
        __syncthreads();
        acc += other;
        lds[t] = acc;
        __syncthreads();
    }
    if (t < NBLK) partials[t] = acc - val;
}

// ---- Phase 2c: add block bases; init cursors ----------------------------
__global__ void fixup_kernel(int* __restrict__ off,
                             const int* __restrict__ partials,
                             int* __restrict__ cursor) {
    int i = blockIdx.x * blockDim.x + threadIdx.x;
    if (i < N_NODES) {
        int v = off[i] + partials[i / ELEMS_PER_BLOCK];
        off[i] = v;
        cursor[i] = v;
    }
}

// ---- Phase 3: bucket-scatter packed (src, w) into dst-sorted order ------
// 1 edge/thread: 19.5K waves give the L3 atomic round-trip full latency hiding.
__global__ void scatter_edges_kernel(const int* __restrict__ src,
                                     const int* __restrict__ dst,
                                     const float* __restrict__ ew,
                                     int* __restrict__ cursor,
                                     u64* __restrict__ edges) {
    int e = blockIdx.x * blockDim.x + threadIdx.x;
    if (e >= N_EDGES) return;
    int s = src[e];
    int d = dst[e];
    float w = ew[e];
    int pos = atomicAdd(&cursor[d], 1);
    edges[pos] = (u64)(unsigned)s | ((u64)__float_as_uint(w) << 32);
}

// ---- Phase 4: gather-aggregate + fused L2 normalize ---------------------
// 16 lanes per node (lane = dim quad, float4 each), 4 nodes per wave.
__global__ void aggregate_kernel(const float* __restrict__ user_emb,
                                 const float* __restrict__ item_emb,
                                 const int* __restrict__ off,
                                 const int* __restrict__ deg,
                                 const u64* __restrict__ edges,
                                 float* __restrict__ out) {
    int gtid = blockIdx.x * blockDim.x + threadIdx.x;
    int node = gtid >> 4;          // 16 threads per node
    int q    = threadIdx.x & 15;   // dim quad: dims [4q, 4q+3]
    if (node >= N_NODES) return;

    int start = off[node];
    int n     = deg[node];

    float4 acc = make_float4(0.f, 0.f, 0.f, 0.f);

    int j = 0;
    for (; j + 2 <= n; j += 2) {
        u64 pk0 = edges[start + j];
        u64 pk1 = edges[start + j + 1];
        int s0 = (int)(unsigned)(pk0 & 0xffffffffULL);
        int s1 = (int)(unsigned)(pk1 & 0xffffffffULL);
        float w0 = __uint_as_float((unsigned)(pk0 >> 32));
        float w1 = __uint_as_float((unsigned)(pk1 >> 32));
        const float* r0 = (s0 < N_USERS) ? user_emb + (size_t)s0 * DIM
                                         : item_emb + (size_t)(s0 - N_USERS) * DIM;
        const float* r1 = (s1 < N_USERS) ? user_emb + (size_t)s1 * DIM
                                         : item_emb + (size_t)(s1 - N_USERS) * DIM;
        float4 v0 = *reinterpret_cast<const float4*>(r0 + q * 4);
        float4 v1 = *reinterpret_cast<const float4*>(r1 + q * 4);
        acc.x = fmaf(w0, v0.x, acc.x);
        acc.y = fmaf(w0, v0.y, acc.y);
        acc.z = fmaf(w0, v0.z, acc.z);
        acc.w = fmaf(w0, v0.w, acc.w);
        acc.x = fmaf(w1, v1.x, acc.x);
        acc.y = fmaf(w1, v1.y, acc.y);
        acc.z = fmaf(w1, v1.z, acc.z);
        acc.w = fmaf(w1, v1.w, acc.w);
    }
    if (j < n) {
        u64 pk = edges[start + j];
        int s = (int)(unsigned)(pk & 0xffffffffULL);
        float w = __uint_as_float((unsigned)(pk >> 32));
        const float* r = (s < N_USERS) ? user_emb + (size_t)s * DIM
                                       : item_emb + (size_t)(s - N_USERS) * DIM;
        float4 v = *reinterpret_cast<const float4*>(r + q * 4);
        acc.x = fmaf(w, v.x, acc.x);
        acc.y = fmaf(w, v.y, acc.y);
        acc.z = fmaf(w, v.z, acc.z);
        acc.w = fmaf(w, v.w, acc.w);
    }

    float ss = acc.x * acc.x + acc.y * acc.y + acc.z * acc.z + acc.w * acc.w;
    #pragma unroll
    for (int o = 8; o >= 1; o >>= 1)
        ss += __shfl_xor(ss, o, 64);

    float denom = fmaxf(sqrtf(ss), EPS);
    float inv = 1.0f / denom;
    float4 r;
    r.x = acc.x * inv; r.y = acc.y * inv; r.z = acc.z * inv; r.w = acc.w * inv;
    *reinterpret_cast<float4*>(out + (size_t)node * DIM + q * 4) = r;
}

extern "C" void kernel_launch(void* const* d_in, const int* in_sizes, int n_in,
                              void* d_out, int out_size, void* d_ws, size_t ws_size,
                              hipStream_t stream) {
    const float* user_emb = (const float*)d_in[0];
    const float* item_emb = (const float*)d_in[1];
    const int* src        = (const int*)d_in[2];
    const int* dst        = (const int*)d_in[3];
    const float* ew       = (const float*)d_in[4];
    float* out            = (float*)d_out;

    // Workspace (ints): off[N] | deg[N] | cursor[N] | partials[512] | edges[E] (8B)
    int* off      = (int*)d_ws;
    int* deg      = off + N_NODES;
    int* cursor   = deg + N_NODES;
    int* partials = cursor + N_NODES;
    u64* edges    = (u64*)(partials + 512);

    hipMemsetAsync(deg, 0, (size_t)N_NODES * sizeof(int), stream);

    {   // histogram (1 edge/thread)
        int block = 256, grid = (N_EDGES + block - 1) / block;
        hist_kernel<<<grid, block, 0, stream>>>(dst, deg);
    }
    {   // scan
        scan_block_kernel<<<NBLK, SCAN_THREADS, 0, stream>>>(deg, off, partials);
        scan_partials_kernel<<<1, 512, 0, stream>>>(partials);
        int block = 256, grid = (N_NODES + block - 1) / block;
        fixup_kernel<<<grid, block, 0, stream>>>(off, partials, cursor);
    }
    {   // bucket scatter (1 edge/thread for max latency hiding)
        int block = 256, grid = (N_EDGES + block - 1) / block;
        scatter_edges_kernel<<<grid, block, 0, stream>>>(src, dst, ew, cursor, edges);
    }
    {   // gather-aggregate + normalize (16 threads/node)
        long long total = (long long)N_NODES * 16;
        int block = 256;
        int grid = (int)((total + block - 1) / block);
        aggregate_kernel<<<grid, block, 0, stream>>>(user_emb, item_emb, off, deg, edges, out);
    }
}

// Round 14
// 308.303 us; speedup vs baseline: 3.9498x; 1.0843x over previous
//
#include <hip/hip_runtime.h>

#define N_USERS 200000
#define N_ITEMS 100000
#define N_NODES (N_USERS + N_ITEMS)
#define N_EDGES 1250000
#define DIM 64
#define EPS 1e-12f

#define SCAN_THREADS 256
#define ELEMS_PER_THREAD 4
#define ELEMS_PER_BLOCK (SCAN_THREADS * ELEMS_PER_THREAD)   // 1024
#define NBLK ((N_NODES + ELEMS_PER_BLOCK - 1) / ELEMS_PER_BLOCK)  // 293

#define NPART 8
#define NODES_PER_PART (N_NODES / NPART)   // 37500 exactly
#define SCAT_BLOCKS 2048                    // multiple of 8; 256/partition

typedef unsigned long long u64;

// ---- Phase 1: histogram of dst (1 edge/thread) --------------------------
__global__ void hist_kernel(const int* __restrict__ dst, int* __restrict__ deg) {
    int e = blockIdx.x * blockDim.x + threadIdx.x;
    if (e < N_EDGES) atomicAdd(&deg[dst[e]], 1);
}

// ---- Phase 2a: per-block exclusive scan of deg --------------------------
__global__ void scan_block_kernel(const int* __restrict__ deg,
                                  int* __restrict__ off,
                                  int* __restrict__ partials) {
    __shared__ int lds[SCAN_THREADS];
    int t = threadIdx.x;
    int base = blockIdx.x * ELEMS_PER_BLOCK + t * ELEMS_PER_THREAD;

    int v[ELEMS_PER_THREAD];
    #pragma unroll
    for (int k = 0; k < ELEMS_PER_THREAD; k++) {
        int i = base + k;
        v[k] = (i < N_NODES) ? deg[i] : 0;
    }
    int tsum = v[0] + v[1] + v[2] + v[3];

    int val = tsum;
    lds[t] = val;
    __syncthreads();
    for (int o = 1; o < SCAN_THREADS; o <<= 1) {
        int other = (t >= o) ? lds[t - o] : 0;
        __syncthreads();
        val += other;
        lds[t] = val;
        __syncthreads();
    }
    int run = val - tsum;
    #pragma unroll
    for (int k = 0; k < ELEMS_PER_THREAD; k++) {
        int i = base + k;
        if (i < N_NODES) off[i] = run;
        run += v[k];
    }
    if (t == SCAN_THREADS - 1) partials[blockIdx.x] = val;
}

// ---- Phase 2b: exclusive scan of the 293 block totals (one block) -------
__global__ void scan_partials_kernel(int* __restrict__ partials) {
    __shared__ int lds[512];
    int t = threadIdx.x;
    int val = (t < NBLK) ? partials[t] : 0;
    int acc = val;
    lds[t] = acc;
    __syncthreads();
    for (int o = 1; o < 512; o <<= 1) {
        int other = (t >= o) ? lds[t - o] : 0;
        __syncthreads();
        acc += other;
        lds[t] = acc;
        __syncthreads();
    }
    if (t < NBLK) partials[t] = acc - val;
}

// ---- Phase 2c: add block bases; init cursors ----------------------------
__global__ void fixup_kernel(int* __restrict__ off,
                             const int* __restrict__ partials,
                             int* __restrict__ cursor) {
    int i = blockIdx.x * blockDim.x + threadIdx.x;
    if (i < N_NODES) {
        int v = off[i] + partials[i / ELEMS_PER_BLOCK];
        off[i] = v;
        cursor[i] = v;
    }
}

// ---- Phase 3: XCD-partitioned bucket-scatter ----------------------------
// Partition p = blockIdx.x % 8 handles dst in [p*37500, (p+1)*37500).
// Default round-robin block->XCD dispatch puts all of partition p's blocks
// on XCD p, so its random writes/atomics hit a 1.25MB+150KB window resident
// in that XCD's private L2 -> writeback ~10MB total instead of 82MB of
// random 64B lines (measured random-line HBM writeback ceiling ~1.2 TB/s).
// Each partition re-reads all edges (8x15MB, L3-served). Correctness does
// not depend on the XCD mapping.
__global__ void scatter_part_kernel(const int* __restrict__ src,
                                    const int* __restrict__ dst,
                                    const float* __restrict__ ew,
                                    int* __restrict__ cursor,
                                    u64* __restrict__ edges) {
    int part = blockIdx.x & (NPART - 1);
    int rank = blockIdx.x >> 3;                       // block rank within partition
    int tid_p = rank * blockDim.x + threadIdx.x;      // thread id within partition
    int nthreads_p = (SCAT_BLOCKS / NPART) * blockDim.x;  // 65536

    int lo = part * NODES_PER_PART;
    int hi = lo + NODES_PER_PART;

    for (int e = tid_p; e < N_EDGES; e += nthreads_p) {
        int d = dst[e];
        if (d >= lo && d < hi) {
            int s = src[e];
            float w = ew[e];
            int pos = atomicAdd(&cursor[d], 1);
            edges[pos] = (u64)(unsigned)s | ((u64)__float_as_uint(w) << 32);
        }
    }
}

// ---- Phase 4: gather-aggregate + fused L2 normalize ---------------------
// 16 lanes per node (lane = dim quad, float4 each), 4 nodes per wave.
__global__ void aggregate_kernel(const float* __restrict__ user_emb,
                                 const float* __restrict__ item_emb,
                                 const int* __restrict__ off,
                                 const int* __restrict__ deg,
                                 const u64* __restrict__ edges,
                                 float* __restrict__ out) {
    int gtid = blockIdx.x * blockDim.x + threadIdx.x;
    int node = gtid >> 4;          // 16 threads per node
    int q    = threadIdx.x & 15;   // dim quad: dims [4q, 4q+3]
    if (node >= N_NODES) return;

    int start = off[node];
    int n     = deg[node];

    float4 acc = make_float4(0.f, 0.f, 0.f, 0.f);

    int j = 0;
    for (; j + 2 <= n; j += 2) {
        u64 pk0 = edges[start + j];
        u64 pk1 = edges[start + j + 1];
        int s0 = (int)(unsigned)(pk0 & 0xffffffffULL);
        int s1 = (int)(unsigned)(pk1 & 0xffffffffULL);
        float w0 = __uint_as_float((unsigned)(pk0 >> 32));
        float w1 = __uint_as_float((unsigned)(pk1 >> 32));
        const float* r0 = (s0 < N_USERS) ? user_emb + (size_t)s0 * DIM
                                         : item_emb + (size_t)(s0 - N_USERS) * DIM;
        const float* r1 = (s1 < N_USERS) ? user_emb + (size_t)s1 * DIM
                                         : item_emb + (size_t)(s1 - N_USERS) * DIM;
        float4 v0 = *reinterpret_cast<const float4*>(r0 + q * 4);
        float4 v1 = *reinterpret_cast<const float4*>(r1 + q * 4);
        acc.x = fmaf(w0, v0.x, acc.x);
        acc.y = fmaf(w0, v0.y, acc.y);
        acc.z = fmaf(w0, v0.z, acc.z);
        acc.w = fmaf(w0, v0.w, acc.w);
        acc.x = fmaf(w1, v1.x, acc.x);
        acc.y = fmaf(w1, v1.y, acc.y);
        acc.z = fmaf(w1, v1.z, acc.z);
        acc.w = fmaf(w1, v1.w, acc.w);
    }
    if (j < n) {
        u64 pk = edges[start + j];
        int s = (int)(unsigned)(pk & 0xffffffffULL);
        float w = __uint_as_float((unsigned)(pk >> 32));
        const float* r = (s < N_USERS) ? user_emb + (size_t)s * DIM
                                       : item_emb + (size_t)(s - N_USERS) * DIM;
        float4 v = *reinterpret_cast<const float4*>(r + q * 4);
        acc.x = fmaf(w, v.x, acc.x);
        acc.y = fmaf(w, v.y, acc.y);
        acc.z = fmaf(w, v.z, acc.z);
        acc.w = fmaf(w, v.w, acc.w);
    }

    float ss = acc.x * acc.x + acc.y * acc.y + acc.z * acc.z + acc.w * acc.w;
    #pragma unroll
    for (int o = 8; o >= 1; o >>= 1)
        ss += __shfl_xor(ss, o, 64);

    float denom = fmaxf(sqrtf(ss), EPS);
    float inv = 1.0f / denom;
    float4 r;
    r.x = acc.x * inv; r.y = acc.y * inv; r.z = acc.z * inv; r.w = acc.w * inv;
    *reinterpret_cast<float4*>(out + (size_t)node * DIM + q * 4) = r;
}

extern "C" void kernel_launch(void* const* d_in, const int* in_sizes, int n_in,
                              void* d_out, int out_size, void* d_ws, size_t ws_size,
                              hipStream_t stream) {
    const float* user_emb = (const float*)d_in[0];
    const float* item_emb = (const float*)d_in[1];
    const int* src        = (const int*)d_in[2];
    const int* dst        = (const int*)d_in[3];
    const float* ew       = (const float*)d_in[4];
    float* out            = (float*)d_out;

    // Workspace (ints): off[N] | deg[N] | cursor[N] | partials[512] | edges[E] (8B)
    int* off      = (int*)d_ws;
    int* deg      = off + N_NODES;
    int* cursor   = deg + N_NODES;
    int* partials = cursor + N_NODES;
    u64* edges    = (u64*)(partials + 512);

    hipMemsetAsync(deg, 0, (size_t)N_NODES * sizeof(int), stream);

    {   // histogram (1 edge/thread)
        int block = 256, grid = (N_EDGES + block - 1) / block;
        hist_kernel<<<grid, block, 0, stream>>>(dst, deg);
    }
    {   // scan
        scan_block_kernel<<<NBLK, SCAN_THREADS, 0, stream>>>(deg, off, partials);
        scan_partials_kernel<<<1, 512, 0, stream>>>(partials);
        int block = 256, grid = (N_NODES + block - 1) / block;
        fixup_kernel<<<grid, block, 0, stream>>>(off, partials, cursor);
    }
    {   // XCD-partitioned bucket scatter
        scatter_part_kernel<<<SCAT_BLOCKS, 256, 0, stream>>>(src, dst, ew, cursor, edges);
    }
    {   // gather-aggregate + normalize (16 threads/node)
        long long total = (long long)N_NODES * 16;
        int block = 256;
        int grid = (int)((total + block - 1) / block);
        aggregate_kernel<<<grid, block, 0, stream>>>(user_emb, item_emb, off, deg, edges, out);
    }
}

// Round 15
// 305.696 us; speedup vs baseline: 3.9835x; 1.0085x over previous
//
#include <hip/hip_runtime.h>
#include <hip/hip_fp16.h>

#define N_USERS 200000
#define N_ITEMS 100000
#define N_NODES (N_USERS + N_ITEMS)
#define N_EDGES 1250000
#define DIM 64
#define EPS 1e-12f

#define SCAN_THREADS 256
#define ELEMS_PER_THREAD 4
#define ELEMS_PER_BLOCK (SCAN_THREADS * ELEMS_PER_THREAD)   // 1024
#define NBLK ((N_NODES + ELEMS_PER_BLOCK - 1) / ELEMS_PER_BLOCK)  // 293

#define NPART 8
#define NODES_PER_PART (N_NODES / NPART)   // 37500 exactly
#define SCAT_BLOCKS 2048                    // multiple of 8; 256/partition

typedef unsigned long long u64;

// ---- Phase 0: convert f32 table -> fp16 (halves gather line traffic) ----
// Flat concat layout: elements [0, N_USERS*64) from user_emb, rest item_emb.
__global__ void convert_kernel(const float4* __restrict__ user4,
                               const float4* __restrict__ item4,
                               __half* __restrict__ ht) {
    int i = blockIdx.x * blockDim.x + threadIdx.x;   // quad index
    const int nuq = N_USERS * DIM / 4;               // user quads
    const int ntq = N_NODES * DIM / 4;
    if (i >= ntq) return;
    float4 v = (i < nuq) ? user4[i] : item4[i - nuq];
    __half2 h01 = __floats2half2_rn(v.x, v.y);
    __half2 h23 = __floats2half2_rn(v.z, v.w);
    uint2 packed;
    packed.x = *reinterpret_cast<unsigned*>(&h01);
    packed.y = *reinterpret_cast<unsigned*>(&h23);
    *reinterpret_cast<uint2*>(ht + (size_t)i * 4) = packed;
}

// ---- Phase 1: histogram of dst (1 edge/thread) --------------------------
__global__ void hist_kernel(const int* __restrict__ dst, int* __restrict__ deg) {
    int e = blockIdx.x * blockDim.x + threadIdx.x;
    if (e < N_EDGES) atomicAdd(&deg[dst[e]], 1);
}

// ---- Phase 2a: per-block exclusive scan of deg --------------------------
__global__ void scan_block_kernel(const int* __restrict__ deg,
                                  int* __restrict__ off,
                                  int* __restrict__ partials) {
    __shared__ int lds[SCAN_THREADS];
    int t = threadIdx.x;
    int base = blockIdx.x * ELEMS_PER_BLOCK + t * ELEMS_PER_THREAD;

    int v[ELEMS_PER_THREAD];
    #pragma unroll
    for (int k = 0; k < ELEMS_PER_THREAD; k++) {
        int i = base + k;
        v[k] = (i < N_NODES) ? deg[i] : 0;
    }
    int tsum = v[0] + v[1] + v[2] + v[3];

    int val = tsum;
    lds[t] = val;
    __syncthreads();
    for (int o = 1; o < SCAN_THREADS; o <<= 1) {
        int other = (t >= o) ? lds[t - o] : 0;
        __syncthreads();
        val += other;
        lds[t] = val;
        __syncthreads();
    }
    int run = val - tsum;
    #pragma unroll
    for (int k = 0; k < ELEMS_PER_THREAD; k++) {
        int i = base + k;
        if (i < N_NODES) off[i] = run;
        run += v[k];
    }
    if (t == SCAN_THREADS - 1) partials[blockIdx.x] = val;
}

// ---- Phase 2b: exclusive scan of the 293 block totals (one block) -------
__global__ void scan_partials_kernel(int* __restrict__ partials) {
    __shared__ int lds[512];
    int t = threadIdx.x;
    int val = (t < NBLK) ? partials[t] : 0;
    int acc = val;
    lds[t] = acc;
    __syncthreads();
    for (int o = 1; o < 512; o <<= 1) {
        int other = (t >= o) ? lds[t - o] : 0;
        __syncthreads();
        acc += other;
        lds[t] = acc;
        __syncthreads();
    }
    if (t < NBLK) partials[t] = acc - val;
}

// ---- Phase 2c: add block bases; init cursors ----------------------------
__global__ void fixup_kernel(int* __restrict__ off,
                             const int* __restrict__ partials,
                             int* __restrict__ cursor) {
    int i = blockIdx.x * blockDim.x + threadIdx.x;
    if (i < N_NODES) {
        int v = off[i] + partials[i / ELEMS_PER_BLOCK];
        off[i] = v;
        cursor[i] = v;
    }
}

// ---- Phase 3: XCD-partitioned bucket-scatter (as round 14, kept) --------
__global__ void scatter_part_kernel(const int* __restrict__ src,
                                    const int* __restrict__ dst,
                                    const float* __restrict__ ew,
                                    int* __restrict__ cursor,
                                    u64* __restrict__ edges) {
    int part = blockIdx.x & (NPART - 1);
    int rank = blockIdx.x >> 3;
    int tid_p = rank * blockDim.x + threadIdx.x;
    int nthreads_p = (SCAT_BLOCKS / NPART) * blockDim.x;  // 65536

    int lo = part * NODES_PER_PART;
    int hi = lo + NODES_PER_PART;

    for (int e = tid_p; e < N_EDGES; e += nthreads_p) {
        int d = dst[e];
        if (d >= lo && d < hi) {
            int s = src[e];
            float w = ew[e];
            int pos = atomicAdd(&cursor[d], 1);
            edges[pos] = (u64)(unsigned)s | ((u64)__float_as_uint(w) << 32);
        }
    }
}

// ---- Phase 4 (fp16 path): gather-aggregate + fused L2 normalize ---------
// 16 lanes/node; lane q reads 4 halves (8B) -> 2 cache lines per row gather.
__global__ void aggregate_h_kernel(const __half* __restrict__ ht,
                                   const int* __restrict__ off,
                                   const int* __restrict__ deg,
                                   const u64* __restrict__ edges,
                                   float* __restrict__ out) {
    int gtid = blockIdx.x * blockDim.x + threadIdx.x;
    int node = gtid >> 4;
    int q    = threadIdx.x & 15;
    if (node >= N_NODES) return;

    int start = off[node];
    int n     = deg[node];

    float4 acc = make_float4(0.f, 0.f, 0.f, 0.f);

    int j = 0;
    for (; j + 2 <= n; j += 2) {
        u64 pk0 = edges[start + j];
        u64 pk1 = edges[start + j + 1];
        int s0 = (int)(unsigned)(pk0 & 0xffffffffULL);
        int s1 = (int)(unsigned)(pk1 & 0xffffffffULL);
        float w0 = __uint_as_float((unsigned)(pk0 >> 32));
        float w1 = __uint_as_float((unsigned)(pk1 >> 32));
        uint2 hv0 = *reinterpret_cast<const uint2*>(ht + (size_t)s0 * DIM + q * 4);
        uint2 hv1 = *reinterpret_cast<const uint2*>(ht + (size_t)s1 * DIM + q * 4);
        __half2 a0 = *reinterpret_cast<__half2*>(&hv0.x);
        __half2 b0 = *reinterpret_cast<__half2*>(&hv0.y);
        __half2 a1 = *reinterpret_cast<__half2*>(&hv1.x);
        __half2 b1 = *reinterpret_cast<__half2*>(&hv1.y);
        float2 f0a = __half22float2(a0), f0b = __half22float2(b0);
        float2 f1a = __half22float2(a1), f1b = __half22float2(b1);
        acc.x = fmaf(w0, f0a.x, acc.x);
        acc.y = fmaf(w0, f0a.y, acc.y);
        acc.z = fmaf(w0, f0b.x, acc.z);
        acc.w = fmaf(w0, f0b.y, acc.w);
        acc.x = fmaf(w1, f1a.x, acc.x);
        acc.y = fmaf(w1, f1a.y, acc.y);
        acc.z = fmaf(w1, f1b.x, acc.z);
        acc.w = fmaf(w1, f1b.y, acc.w);
    }
    if (j < n) {
        u64 pk = edges[start + j];
        int s = (int)(unsigned)(pk & 0xffffffffULL);
        float w = __uint_as_float((unsigned)(pk >> 32));
        uint2 hv = *reinterpret_cast<const uint2*>(ht + (size_t)s * DIM + q * 4);
        __half2 a = *reinterpret_cast<__half2*>(&hv.x);
        __half2 b = *reinterpret_cast<__half2*>(&hv.y);
        float2 fa = __half22float2(a), fb = __half22float2(b);
        acc.x = fmaf(w, fa.x, acc.x);
        acc.y = fmaf(w, fa.y, acc.y);
        acc.z = fmaf(w, fb.x, acc.z);
        acc.w = fmaf(w, fb.y, acc.w);
    }

    float ss = acc.x * acc.x + acc.y * acc.y + acc.z * acc.z + acc.w * acc.w;
    #pragma unroll
    for (int o = 8; o >= 1; o >>= 1)
        ss += __shfl_xor(ss, o, 64);

    float denom = fmaxf(sqrtf(ss), EPS);
    float inv = 1.0f / denom;
    float4 r;
    r.x = acc.x * inv; r.y = acc.y * inv; r.z = acc.z * inv; r.w = acc.w * inv;
    *reinterpret_cast<float4*>(out + (size_t)node * DIM + q * 4) = r;
}

// ---- Phase 4 (f32 fallback, byte-identical to round 14) -----------------
__global__ void aggregate_kernel(const float* __restrict__ user_emb,
                                 const float* __restrict__ item_emb,
                                 const int* __restrict__ off,
                                 const int* __restrict__ deg,
                                 const u64* __restrict__ edges,
                                 float* __restrict__ out) {
    int gtid = blockIdx.x * blockDim.x + threadIdx.x;
    int node = gtid >> 4;
    int q    = threadIdx.x & 15;
    if (node >= N_NODES) return;

    int start = off[node];
    int n     = deg[node];

    float4 acc = make_float4(0.f, 0.f, 0.f, 0.f);

    int j = 0;
    for (; j + 2 <= n; j += 2) {
        u64 pk0 = edges[start + j];
        u64 pk1 = edges[start + j + 1];
        int s0 = (int)(unsigned)(pk0 & 0xffffffffULL);
        int s1 = (int)(unsigned)(pk1 & 0xffffffffULL);
        float w0 = __uint_as_float((unsigned)(pk0 >> 32));
        float w1 = __uint_as_float((unsigned)(pk1 >> 32));
        const float* r0 = (s0 < N_USERS) ? user_emb + (size_t)s0 * DIM
                                         : item_emb + (size_t)(s0 - N_USERS) * DIM;
        const float* r1 = (s1 < N_USERS) ? user_emb + (size_t)s1 * DIM
                                         : item_emb + (size_t)(s1 - N_USERS) * DIM;
        float4 v0 = *reinterpret_cast<const float4*>(r0 + q * 4);
        float4 v1 = *reinterpret_cast<const float4*>(r1 + q * 4);
        acc.x = fmaf(w0, v0.x, acc.x);
        acc.y = fmaf(w0, v0.y, acc.y);
        acc.z = fmaf(w0, v0.z, acc.z);
        acc.w = fmaf(w0, v0.w, acc.w);
        acc.x = fmaf(w1, v1.x, acc.x);
        acc.y = fmaf(w1, v1.y, acc.y);
        acc.z = fmaf(w1, v1.z, acc.z);
        acc.w = fmaf(w1, v1.w, acc.w);
    }
    if (j < n) {
        u64 pk = edges[start + j];
        int s = (int)(unsigned)(pk & 0xffffffffULL);
        float w = __uint_as_float((unsigned)(pk >> 32));
        const float* r = (s < N_USERS) ? user_emb + (size_t)s * DIM
                                       : item_emb + (size_t)(s - N_USERS) * DIM;
        float4 v = *reinterpret_cast<const float4*>(r + q * 4);
        acc.x = fmaf(w, v.x, acc.x);
        acc.y = fmaf(w, v.y, acc.y);
        acc.z = fmaf(w, v.z, acc.z);
        acc.w = fmaf(w, v.w, acc.w);
    }

    float ss = acc.x * acc.x + acc.y * acc.y + acc.z * acc.z + acc.w * acc.w;
    #pragma unroll
    for (int o = 8; o >= 1; o >>= 1)
        ss += __shfl_xor(ss, o, 64);

    float denom = fmaxf(sqrtf(ss), EPS);
    float inv = 1.0f / denom;
    float4 r;
    r.x = acc.x * inv; r.y = acc.y * inv; r.z = acc.z * inv; r.w = acc.w * inv;
    *reinterpret_cast<float4*>(out + (size_t)node * DIM + q * 4) = r;
}

extern "C" void kernel_launch(void* const* d_in, const int* in_sizes, int n_in,
                              void* d_out, int out_size, void* d_ws, size_t ws_size,
                              hipStream_t stream) {
    const float* user_emb = (const float*)d_in[0];
    const float* item_emb = (const float*)d_in[1];
    const int* src        = (const int*)d_in[2];
    const int* dst        = (const int*)d_in[3];
    const float* ew       = (const float*)d_in[4];
    float* out            = (float*)d_out;

    // Workspace: off[N] | deg[N] | cursor[N] | partials[512] | edges[E] (8B) | ht (fp16 table)
    int* off      = (int*)d_ws;
    int* deg      = off + N_NODES;
    int* cursor   = deg + N_NODES;
    int* partials = cursor + N_NODES;
    u64* edges    = (u64*)(partials + 512);
    __half* ht    = (__half*)(edges + N_EDGES);

    const size_t base_bytes = (size_t)(3 * N_NODES + 512) * 4 + (size_t)N_EDGES * 8;
    const size_t need_fp16  = base_bytes + (size_t)N_NODES * DIM * 2;
    const bool use_fp16 = (ws_size >= need_fp16);   // constant per process -> graph-safe

    hipMemsetAsync(deg, 0, (size_t)N_NODES * sizeof(int), stream);

    if (use_fp16) {   // table f32 -> fp16 (runs concurrently-ish with hist/scan chain)
        int quads = N_NODES * DIM / 4;
        int block = 256, grid = (quads + block - 1) / block;
        convert_kernel<<<grid, block, 0, stream>>>(
            (const float4*)user_emb, (const float4*)item_emb, ht);
    }
    {   // histogram (1 edge/thread)
        int block = 256, grid = (N_EDGES + block - 1) / block;
        hist_kernel<<<grid, block, 0, stream>>>(dst, deg);
    }
    {   // scan
        scan_block_kernel<<<NBLK, SCAN_THREADS, 0, stream>>>(deg, off, partials);
        scan_partials_kernel<<<1, 512, 0, stream>>>(partials);
        int block = 256, grid = (N_NODES + block - 1) / block;
        fixup_kernel<<<grid, block, 0, stream>>>(off, partials, cursor);
    }
    {   // XCD-partitioned bucket scatter
        scatter_part_kernel<<<SCAT_BLOCKS, 256, 0, stream>>>(src, dst, ew, cursor, edges);
    }
    {   // gather-aggregate + normalize (16 threads/node)
        long long total = (long long)N_NODES * 16;
        int block = 256;
        int grid = (int)((total + block - 1) / block);
        if (use_fp16)
            aggregate_h_kernel<<<grid, block, 0, stream>>>(ht, off, deg, edges, out);
        else
            aggregate_kernel<<<grid, block, 0, stream>>>(user_emb, item_emb, off, deg, edges, out);
    }
}